// Round 2
// baseline (2554.912 us; speedup 1.0000x reference)
//
#include <hip/hip_runtime.h>

#define N_ENT 100000
#define N_USR 50000
#define NE    600000
#define NUI   500000
#define DD    128

// ---------------- atomic float max via int tricks ----------------
// Branch on the BIT pattern so -0.0 takes the unsigned-min path (correct).
__device__ __forceinline__ void atomicMaxF(float* addr, float v) {
  int bits = __float_as_int(v);
  if (bits >= 0) atomicMax((int*)addr, bits);
  else           atomicMin((unsigned int*)addr, (unsigned int)bits);
}

// ---------------- fill m = -inf, denom = 0 ----------------
__global__ void k_fill(float* __restrict__ m, float* __restrict__ denom, int n) {
  int i = blockIdx.x * 256 + threadIdx.x;
  if (i < n) { m[i] = __int_as_float(0xFF800000); denom[i] = 0.0f; }
}

// ---------------- T = A @ W  (A: nrows x 128, W: 128 x 128) ----------------
// block: 256 threads; tile: 64 rows x 128 cols; thread: 16 rows x 2 cols.
__global__ __launch_bounds__(256) void k_gemm(const float* __restrict__ A,
                                              const float* __restrict__ W,
                                              float* __restrict__ T, int nrows) {
  __shared__ float As[64 * DD];
  const int tid = threadIdx.x;
  const int cp  = tid & 63;   // cols 2cp, 2cp+1
  const int rg  = tid >> 6;   // wave id 0..3 -> rows rg*16 .. rg*16+15
  const long row0 = (long)blockIdx.x * 64;
  const int maxr = nrows - 1;

  #pragma unroll
  for (int j = 0; j < 8; ++j) {            // stage 64x128 tile as float4
    int idx4 = j * 256 + tid;              // < 2048
    int r = idx4 >> 5, k4 = idx4 & 31;
    long rr = row0 + r; if (rr > maxr) rr = maxr;
    ((float4*)As)[idx4] = ((const float4*)(A + rr * DD))[k4];
  }
  __syncthreads();

  float2 acc[16];
  #pragma unroll
  for (int r = 0; r < 16; ++r) acc[r] = make_float2(0.f, 0.f);

  const float* Abase = As + rg * 16 * DD;
  for (int k4 = 0; k4 < 32; ++k4) {
    float2 w[4];
    #pragma unroll
    for (int kk = 0; kk < 4; ++kk)
      w[kk] = ((const float2*)(W + (k4 * 4 + kk) * DD))[cp];  // coalesced, L1-hot
    #pragma unroll
    for (int r = 0; r < 16; ++r) {
      float4 a = *(const float4*)(Abase + r * DD + k4 * 4);   // wave-uniform broadcast
      acc[r].x += a.x * w[0].x + a.y * w[1].x + a.z * w[2].x + a.w * w[3].x;
      acc[r].y += a.x * w[0].y + a.y * w[1].y + a.z * w[2].y + a.w * w[3].y;
    }
  }

  #pragma unroll
  for (int r = 0; r < 16; ++r) {
    long rr = row0 + rg * 16 + r;
    if (rr < nrows) ((float2*)(T + rr * DD))[cp] = acc[r];
  }
}

// ---------------- per-edge attention score + segment max ----------------
// one edge per 64-lane wave; lane l covers dims 2l,2l+1 (lanes 0..31 head0, 32..63 head1)
__global__ __launch_bounds__(256) void k_score(const float* __restrict__ T,
                                               const float* __restrict__ rel,
                                               const int* __restrict__ ei,
                                               const int* __restrict__ et,
                                               float* __restrict__ score,
                                               float* __restrict__ m) {
  int w = (blockIdx.x * 256 + threadIdx.x) >> 6;
  int lane = threadIdx.x & 63;
  if (w >= NE) return;
  int head = ei[w], tail = ei[NE + w], rt = et[w];
  float2 q = ((const float2*)(T + (long)head * DD))[lane];
  float2 t = ((const float2*)(T + (long)tail * DD))[lane];
  float2 r = ((const float2*)(rel + rt * DD))[lane];
  float s = q.x * (t.x * r.x) + q.y * (t.y * r.y);
  s += __shfl_xor(s, 16, 32);
  s += __shfl_xor(s, 8, 32);
  s += __shfl_xor(s, 4, 32);
  s += __shfl_xor(s, 2, 32);
  s += __shfl_xor(s, 1, 32);
  if (lane == 0 || lane == 32) {
    int h = lane >> 5;
    float sc = s * 0.125f;                 // 1/sqrt(64)
    score[w * 2 + h] = sc;
    atomicMaxF(&m[head * 2 + h], sc);
  }
}

// ---------------- ex = exp(score - m[head]); denom += ex ----------------
__global__ void k_exp(const int* __restrict__ ei, float* __restrict__ score,
                      const float* __restrict__ m, float* __restrict__ denom) {
  int idx = blockIdx.x * 256 + threadIdx.x;
  if (idx >= NE * 2) return;
  int e = idx >> 1, h = idx & 1;
  int head = ei[e];
  float ex = expf(score[idx] - m[head * 2 + h]);
  score[idx] = ex;
  atomicAdd(&denom[head * 2 + h], ex);
}

// ---------------- weighted value scatter-sum into agg ----------------
__global__ __launch_bounds__(256) void k_agg(const float* __restrict__ ent,
                                             const float* __restrict__ rel,
                                             const int* __restrict__ ei,
                                             const int* __restrict__ et,
                                             const float* __restrict__ score,
                                             const float* __restrict__ denom,
                                             float* __restrict__ agg) {
  int w = (blockIdx.x * 256 + threadIdx.x) >> 6;
  int lane = threadIdx.x & 63;
  if (w >= NE) return;
  int head = ei[w], tail = ei[NE + w], rt = et[w];
  int h = lane >> 5;
  float a = score[w * 2 + h] / denom[head * 2 + h];
  float2 v = ((const float2*)(ent + (long)tail * DD))[lane];
  float2 r = ((const float2*)(rel + rt * DD))[lane];
  float* dst = agg + (long)head * DD + lane * 2;
  atomicAdd(dst,     v.x * r.x * a);
  atomicAdd(dst + 1, v.y * r.y * a);
}

// ---------------- user aggregation ----------------
__global__ __launch_bounds__(256) void k_user(const float* __restrict__ ent,
                                              const int* __restrict__ ie,
                                              const float* __restrict__ iw,
                                              float* __restrict__ uagg) {
  int w = (blockIdx.x * 256 + threadIdx.x) >> 6;
  int lane = threadIdx.x & 63;
  if (w >= NUI) return;
  int u = ie[w], i = ie[NUI + w];
  float wt = iw[w];
  float2 v = ((const float2*)(ent + (long)i * DD))[lane];
  float* dst = uagg + (long)u * DD + lane * 2;
  atomicAdd(dst,     wt * v.x);
  atomicAdd(dst + 1, wt * v.y);
}

// ---------------- l2norm + write next + residual add ----------------
__global__ __launch_bounds__(256) void k_norm(const float* __restrict__ agg,
                                              float* __restrict__ next,
                                              float* __restrict__ res, int n) {
  int w = (blockIdx.x * 256 + threadIdx.x) >> 6;
  int lane = threadIdx.x & 63;
  if (w >= n) return;
  float2 v = ((const float2*)(agg + (long)w * DD))[lane];
  float ss = v.x * v.x + v.y * v.y;
  ss += __shfl_xor(ss, 32);
  ss += __shfl_xor(ss, 16);
  ss += __shfl_xor(ss, 8);
  ss += __shfl_xor(ss, 4);
  ss += __shfl_xor(ss, 2);
  ss += __shfl_xor(ss, 1);
  float inv = 1.0f / fmaxf(sqrtf(ss), 1e-12f);
  float2 nv = make_float2(v.x * inv, v.y * inv);
  if (next) ((float2*)(next + (long)w * DD))[lane] = nv;
  float2* rp = ((float2*)(res + (long)w * DD)) + lane;
  float2 cur = *rp;
  cur.x += nv.x; cur.y += nv.y;
  *rp = cur;
}

extern "C" void kernel_launch(void* const* d_in, const int* in_sizes, int n_in,
                              void* d_out, int out_size, void* d_ws, size_t ws_size,
                              hipStream_t stream) {
  const float* user_emb   = (const float*)d_in[0];
  const float* entity_emb = (const float*)d_in[1];
  const float* W_Q        = (const float*)d_in[2];
  const float* rel_emb    = (const float*)d_in[3];
  const int*   edge_index = (const int*)d_in[4];
  const int*   edge_type  = (const int*)d_in[5];
  const int*   inter_edge = (const int*)d_in[6];
  const float* inter_w    = (const float*)d_in[7];

  float* out_user = (float*)d_out;                       // N_USR*DD
  float* out_ent  = out_user + (size_t)N_USR * DD;       // N_ENT*DD

  char* p = (char*)d_ws;
  float* buf0  = (float*)p; p += (size_t)N_ENT * DD * 4;
  float* buf1  = (float*)p; p += (size_t)N_ENT * DD * 4;
  float* uagg  = (float*)p; p += (size_t)N_USR * DD * 4;
  float* score = (float*)p; p += (size_t)NE * 2 * 4;
  float* m     = (float*)p; p += (size_t)N_ENT * 2 * 4;
  float* denom = (float*)p; p += (size_t)N_ENT * 2 * 4;

  // residual init: res = input embeddings
  hipMemcpyAsync(out_user, user_emb, (size_t)N_USR * DD * 4, hipMemcpyDeviceToDevice, stream);
  hipMemcpyAsync(out_ent, entity_emb, (size_t)N_ENT * DD * 4, hipMemcpyDeviceToDevice, stream);

  const float* entC = entity_emb;
  float* bufs[2] = { buf0, buf1 };

  for (int hop = 0; hop < 2; ++hop) {
    float* Tb = bufs[hop];   // holds T during score, then reused as ent_agg

    k_gemm<<<(N_ENT + 63) / 64, 256, 0, stream>>>(entC, W_Q, Tb, N_ENT);
    k_fill<<<(N_ENT * 2 + 255) / 256, 256, 0, stream>>>(m, denom, N_ENT * 2);
    k_score<<<NE / 4, 256, 0, stream>>>(Tb, rel_emb, edge_index, edge_type, score, m);
    k_exp<<<(NE * 2 + 255) / 256, 256, 0, stream>>>(edge_index, score, m, denom);
    hipMemsetAsync(Tb, 0, (size_t)N_ENT * DD * 4, stream);      // T dead -> becomes agg
    k_agg<<<NE / 4, 256, 0, stream>>>(entC, rel_emb, edge_index, edge_type, score, denom, Tb);
    hipMemsetAsync(uagg, 0, (size_t)N_USR * DD * 4, stream);
    k_user<<<NUI / 4, 256, 0, stream>>>(entC, inter_edge, inter_w, uagg);
    k_norm<<<N_ENT / 4, 256, 0, stream>>>(Tb, Tb, out_ent, N_ENT);   // in-place normalize
    k_norm<<<N_USR / 4, 256, 0, stream>>>(uagg, (float*)nullptr, out_user, N_USR);

    entC = Tb;   // normalized entities feed next hop
  }
}

// Round 4
// 956.986 us; speedup vs baseline: 2.6697x; 2.6697x over previous
//
#include <hip/hip_runtime.h>

#define N_ENT 100000
#define N_USR 50000
#define NE    600000
#define NUI   500000
#define DD    128

// ---------------- histogram: deg[key[e]]++ ----------------
__global__ void k_hist(const int* __restrict__ keys, int* __restrict__ deg, int n) {
  int e = blockIdx.x * 256 + threadIdx.x;
  if (e < n) atomicAdd(&deg[keys[e]], 1);
}

// ---------------- exclusive scan (2 independent scans, one block each) ----------------
// block 0: ent degrees (N_ENT), block 1: user degrees (N_USR). 1024 threads.
__global__ __launch_bounds__(1024) void k_scan2(const int* __restrict__ degE, int* __restrict__ startsE,
                                                const int* __restrict__ degU, int* __restrict__ startsU) {
  const int* deg = blockIdx.x ? degU : degE;
  int* starts    = blockIdx.x ? startsU : startsE;
  const int n    = blockIdx.x ? N_USR : N_ENT;

  __shared__ int wsum[16];
  __shared__ int carry;
  const int tid = threadIdx.x, lane = tid & 63, wid = tid >> 6;
  if (tid == 0) carry = 0;
  __syncthreads();

  for (int base = 0; base < n; base += 1024) {
    int i = base + tid;
    int v = (i < n) ? deg[i] : 0;
    int s = v;                       // inclusive scan within wave
    #pragma unroll
    for (int off = 1; off < 64; off <<= 1) {
      int t = __shfl_up(s, off, 64);
      if (lane >= off) s += t;
    }
    if (lane == 63) wsum[wid] = s;
    __syncthreads();
    if (wid == 0) {                  // scan the 16 wave sums
      int ws = (lane < 16) ? wsum[lane] : 0;
      #pragma unroll
      for (int off = 1; off < 16; off <<= 1) {
        int t = __shfl_up(ws, off, 64);
        if (lane >= off) ws += t;
      }
      if (lane < 16) wsum[lane] = ws;
    }
    __syncthreads();
    int excl = carry + (wid ? wsum[wid - 1] : 0) + (s - v);
    if (i < n) starts[i] = excl;
    __syncthreads();
    if (tid == 0) carry += wsum[15];
    __syncthreads();
  }
  if (tid == 0) starts[n] = carry;
}

// ---------------- scatter edge ids into CSR slots ----------------
__global__ void k_scatter(const int* __restrict__ keys, int* __restrict__ cursor,
                          int* __restrict__ eid, int n) {
  int e = blockIdx.x * 256 + threadIdx.x;
  if (e < n) { int pos = atomicAdd(&cursor[keys[e]], 1); eid[pos] = e; }
}

// ---------------- T = A @ W  (A: nrows x 128, W: 128 x 128) ----------------
__global__ __launch_bounds__(256) void k_gemm(const float* __restrict__ A,
                                              const float* __restrict__ W,
                                              float* __restrict__ T, int nrows) {
  __shared__ float As[64 * DD];
  const int tid = threadIdx.x;
  const int cp  = tid & 63;
  const int rg  = tid >> 6;
  const long row0 = (long)blockIdx.x * 64;
  const int maxr = nrows - 1;

  #pragma unroll
  for (int j = 0; j < 8; ++j) {
    int idx4 = j * 256 + tid;
    int r = idx4 >> 5, k4 = idx4 & 31;
    long rr = row0 + r; if (rr > maxr) rr = maxr;
    ((float4*)As)[idx4] = ((const float4*)(A + rr * DD))[k4];
  }
  __syncthreads();

  float2 acc[16];
  #pragma unroll
  for (int r = 0; r < 16; ++r) acc[r] = make_float2(0.f, 0.f);

  const float* Abase = As + rg * 16 * DD;
  for (int k4 = 0; k4 < 32; ++k4) {
    float2 w[4];
    #pragma unroll
    for (int kk = 0; kk < 4; ++kk)
      w[kk] = ((const float2*)(W + (k4 * 4 + kk) * DD))[cp];
    #pragma unroll
    for (int r = 0; r < 16; ++r) {
      float4 a = *(const float4*)(Abase + r * DD + k4 * 4);
      acc[r].x += a.x * w[0].x + a.y * w[1].x + a.z * w[2].x + a.w * w[3].x;
      acc[r].y += a.x * w[0].y + a.y * w[1].y + a.z * w[2].y + a.w * w[3].y;
    }
  }

  #pragma unroll
  for (int r = 0; r < 16; ++r) {
    long rr = row0 + rg * 16 + r;
    if (rr < nrows) ((float2*)(T + rr * DD))[cp] = acc[r];
  }
}

// ---------------- fused per-node: score + online softmax + weighted agg + norm + residual ----
// one 64-lane wave per node; lane covers dims 2l,2l+1; head0 = lanes 0..31, head1 = lanes 32..63
__global__ __launch_bounds__(256) void k_ent_fused(const float* __restrict__ T,
                                                   const float* __restrict__ ent,
                                                   const float* __restrict__ rel,
                                                   const int* __restrict__ ei,
                                                   const int* __restrict__ et,
                                                   const int* __restrict__ starts,
                                                   const int* __restrict__ eid,
                                                   float* __restrict__ next,
                                                   float* __restrict__ res) {
  int node = (blockIdx.x * 256 + threadIdx.x) >> 6;
  int lane = threadIdx.x & 63;
  if (node >= N_ENT) return;
  int s0 = starts[node], s1 = starts[node + 1];

  float2 q = ((const float2*)(T + (long)node * DD))[lane];
  float m = -INFINITY, denom = 0.f;
  float2 acc = make_float2(0.f, 0.f);

  for (int p = s0; p < s1; ++p) {
    int e    = eid[p];
    int tail = ei[NE + e];
    int rt   = et[e];
    float2 r = ((const float2*)(rel + rt * DD))[lane];      // 9 rows -> L1-hot
    float2 t = ((const float2*)(T + (long)tail * DD))[lane];
    float2 v = ((const float2*)(ent + (long)tail * DD))[lane];
    float s = q.x * (t.x * r.x) + q.y * (t.y * r.y);
    s += __shfl_xor(s, 16, 32);
    s += __shfl_xor(s, 8, 32);
    s += __shfl_xor(s, 4, 32);
    s += __shfl_xor(s, 2, 32);
    s += __shfl_xor(s, 1, 32);
    s *= 0.125f;                                            // 1/sqrt(64)
    // online softmax (uniform within each 32-lane half)
    if (s > m) {
      float c = expf(m - s);                                // first iter: exp(-inf)=0
      denom *= c; acc.x *= c; acc.y *= c; m = s;
    }
    float ex = expf(s - m);
    denom += ex;
    acc.x += v.x * r.x * ex;
    acc.y += v.y * r.y * ex;
  }

  float inv_d = (s1 > s0) ? 1.0f / denom : 0.0f;            // deg==0 -> exact 0 row
  acc.x *= inv_d; acc.y *= inv_d;

  // l2 norm over all 128 dims (64 lanes)
  float ss = acc.x * acc.x + acc.y * acc.y;
  ss += __shfl_xor(ss, 32);
  ss += __shfl_xor(ss, 16);
  ss += __shfl_xor(ss, 8);
  ss += __shfl_xor(ss, 4);
  ss += __shfl_xor(ss, 2);
  ss += __shfl_xor(ss, 1);
  float inv = 1.0f / fmaxf(sqrtf(ss), 1e-12f);
  float2 nv = make_float2(acc.x * inv, acc.y * inv);

  if (next) ((float2*)(next + (long)node * DD))[lane] = nv;
  float2* rp = ((float2*)(res + (long)node * DD)) + lane;
  float2 cur = *rp;
  cur.x += nv.x; cur.y += nv.y;
  *rp = cur;
}

// ---------------- fused per-user: weighted agg + norm + residual ----------------
__global__ __launch_bounds__(256) void k_user_fused(const float* __restrict__ ent,
                                                    const int* __restrict__ ie,
                                                    const float* __restrict__ iw,
                                                    const int* __restrict__ starts,
                                                    const int* __restrict__ eid,
                                                    float* __restrict__ res) {
  int u = (blockIdx.x * 256 + threadIdx.x) >> 6;
  int lane = threadIdx.x & 63;
  if (u >= N_USR) return;
  int s0 = starts[u], s1 = starts[u + 1];

  float2 acc = make_float2(0.f, 0.f);
  for (int p = s0; p < s1; ++p) {
    int e = eid[p];
    int i = ie[NUI + e];
    float w = iw[e];
    float2 v = ((const float2*)(ent + (long)i * DD))[lane];
    acc.x += w * v.x; acc.y += w * v.y;
  }

  float ss = acc.x * acc.x + acc.y * acc.y;
  ss += __shfl_xor(ss, 32);
  ss += __shfl_xor(ss, 16);
  ss += __shfl_xor(ss, 8);
  ss += __shfl_xor(ss, 4);
  ss += __shfl_xor(ss, 2);
  ss += __shfl_xor(ss, 1);
  float inv = 1.0f / fmaxf(sqrtf(ss), 1e-12f);   // ss==0 -> nv==0, matches reference
  float2 nv = make_float2(acc.x * inv, acc.y * inv);

  float2* rp = ((float2*)(res + (long)u * DD)) + lane;
  float2 cur = *rp;
  cur.x += nv.x; cur.y += nv.y;
  *rp = cur;
}

extern "C" void kernel_launch(void* const* d_in, const int* in_sizes, int n_in,
                              void* d_out, int out_size, void* d_ws, size_t ws_size,
                              hipStream_t stream) {
  const float* user_emb   = (const float*)d_in[0];
  const float* entity_emb = (const float*)d_in[1];
  const float* W_Q        = (const float*)d_in[2];
  const float* rel_emb    = (const float*)d_in[3];
  const int*   edge_index = (const int*)d_in[4];
  const int*   edge_type  = (const int*)d_in[5];
  const int*   inter_edge = (const int*)d_in[6];
  const float* inter_w    = (const float*)d_in[7];

  float* out_user = (float*)d_out;                       // N_USR*DD
  float* out_ent  = out_user + (size_t)N_USR * DD;       // N_ENT*DD

  char* p = (char*)d_ws;
  float* bufT    = (float*)p; p += (size_t)N_ENT * DD * 4;   // T (per hop)
  float* bufN    = (float*)p; p += (size_t)N_ENT * DD * 4;   // normalized entities hop1
  int* degE      = (int*)p;   p += (size_t)N_ENT * 4;
  int* startsE   = (int*)p;   p += (size_t)(N_ENT + 1) * 4;
  int* cursorE   = (int*)p;   p += (size_t)N_ENT * 4;
  int* eidE      = (int*)p;   p += (size_t)NE * 4;
  int* degU      = (int*)p;   p += (size_t)N_USR * 4;
  int* startsU   = (int*)p;   p += (size_t)(N_USR + 1) * 4;
  int* cursorU   = (int*)p;   p += (size_t)N_USR * 4;
  int* eidU      = (int*)p;   p += (size_t)NUI * 4;

  // residual init: res = input embeddings
  hipMemcpyAsync(out_user, user_emb, (size_t)N_USR * DD * 4, hipMemcpyDeviceToDevice, stream);
  hipMemcpyAsync(out_ent, entity_emb, (size_t)N_ENT * DD * 4, hipMemcpyDeviceToDevice, stream);

  // ---- CSR build (edge topology constant across hops; rebuilt every call) ----
  hipMemsetAsync(degE, 0, (size_t)N_ENT * 4, stream);
  hipMemsetAsync(degU, 0, (size_t)N_USR * 4, stream);
  k_hist<<<(NE + 255) / 256, 256, 0, stream>>>(edge_index, degE, NE);      // keys = head
  k_hist<<<(NUI + 255) / 256, 256, 0, stream>>>(inter_edge, degU, NUI);    // keys = u_idx
  k_scan2<<<2, 1024, 0, stream>>>(degE, startsE, degU, startsU);
  hipMemcpyAsync(cursorE, startsE, (size_t)N_ENT * 4, hipMemcpyDeviceToDevice, stream);
  hipMemcpyAsync(cursorU, startsU, (size_t)N_USR * 4, hipMemcpyDeviceToDevice, stream);
  k_scatter<<<(NE + 255) / 256, 256, 0, stream>>>(edge_index, cursorE, eidE, NE);
  k_scatter<<<(NUI + 255) / 256, 256, 0, stream>>>(inter_edge, cursorU, eidU, NUI);

  // ---- hop 1 ----
  k_gemm<<<(N_ENT + 63) / 64, 256, 0, stream>>>(entity_emb, W_Q, bufT, N_ENT);
  k_ent_fused<<<(N_ENT + 3) / 4, 256, 0, stream>>>(bufT, entity_emb, rel_emb,
                                                   edge_index, edge_type, startsE, eidE,
                                                   bufN, out_ent);
  k_user_fused<<<(N_USR + 3) / 4, 256, 0, stream>>>(entity_emb, inter_edge, inter_w,
                                                    startsU, eidU, out_user);

  // ---- hop 2 (next-buffer not needed after last hop) ----
  k_gemm<<<(N_ENT + 63) / 64, 256, 0, stream>>>(bufN, W_Q, bufT, N_ENT);
  k_ent_fused<<<(N_ENT + 3) / 4, 256, 0, stream>>>(bufT, bufN, rel_emb,
                                                   edge_index, edge_type, startsE, eidE,
                                                   (float*)nullptr, out_ent);
  k_user_fused<<<(N_USR + 3) / 4, 256, 0, stream>>>(bufN, inter_edge, inter_w,
                                                    startsU, eidU, out_user);
}

// Round 5
// 754.589 us; speedup vs baseline: 3.3858x; 1.2682x over previous
//
#include <hip/hip_runtime.h>

#define N_ENT 100000
#define N_USR 50000
#define NE    600000
#define NUI   500000
#define DD    128
#define NW    (N_ENT + N_USR)

// ---------------- histogram both edge sets ----------------
__global__ void k_hist_all(const int* __restrict__ ei, const int* __restrict__ ie,
                           int* __restrict__ degE, int* __restrict__ degU) {
  int i = blockIdx.x * 256 + threadIdx.x;
  if (i < NE) atomicAdd(&degE[ei[i]], 1);
  else if (i < NE + NUI) atomicAdd(&degU[ie[i - NE]], 1);
}

// ---------------- exclusive scan (2 blocks: ent, user); writes starts AND cursor ----------------
__global__ __launch_bounds__(1024) void k_scan2(const int* __restrict__ degE, int* __restrict__ startsE, int* __restrict__ cursorE,
                                                const int* __restrict__ degU, int* __restrict__ startsU, int* __restrict__ cursorU) {
  const int* deg = blockIdx.x ? degU : degE;
  int* starts    = blockIdx.x ? startsU : startsE;
  int* cursor    = blockIdx.x ? cursorU : cursorE;
  const int n    = blockIdx.x ? N_USR : N_ENT;

  __shared__ int wsum[16];
  __shared__ int carry;
  const int tid = threadIdx.x, lane = tid & 63, wid = tid >> 6;
  if (tid == 0) carry = 0;
  __syncthreads();

  for (int base = 0; base < n; base += 1024) {
    int i = base + tid;
    int v = (i < n) ? deg[i] : 0;
    int s = v;
    #pragma unroll
    for (int off = 1; off < 64; off <<= 1) {
      int t = __shfl_up(s, off, 64);
      if (lane >= off) s += t;
    }
    if (lane == 63) wsum[wid] = s;
    __syncthreads();
    if (wid == 0) {
      int ws = (lane < 16) ? wsum[lane] : 0;
      #pragma unroll
      for (int off = 1; off < 16; off <<= 1) {
        int t = __shfl_up(ws, off, 64);
        if (lane >= off) ws += t;
      }
      if (lane < 16) wsum[lane] = ws;
    }
    __syncthreads();
    int excl = carry + (wid ? wsum[wid - 1] : 0) + (s - v);
    if (i < n) { starts[i] = excl; cursor[i] = excl; }
    __syncthreads();
    if (tid == 0) carry += wsum[15];
    __syncthreads();
  }
  if (tid == 0) starts[n] = carry;
}

// ---------------- scatter payloads into CSR slot order ----------------
// entity edges: pack = tail | (rel_type << 20)  (tail < 2^17, rt < 9)
__global__ void k_scatter_all(const int* __restrict__ ei, const int* __restrict__ et,
                              const int* __restrict__ ie, const float* __restrict__ iw,
                              int* __restrict__ cursorE, int* __restrict__ cursorU,
                              int* __restrict__ packE, int* __restrict__ itemU, float* __restrict__ wU) {
  int i = blockIdx.x * 256 + threadIdx.x;
  if (i < NE) {
    int pos = atomicAdd(&cursorE[ei[i]], 1);
    packE[pos] = ei[NE + i] | (et[i] << 20);
  } else if (i < NE + NUI) {
    int j = i - NE;
    int pos = atomicAdd(&cursorU[ie[j]], 1);
    itemU[pos] = ie[NUI + j];
    wU[pos]    = iw[j];
  }
}

// ---------------- T = A @ W  (A: nrows x 128, W: 128 x 128) ----------------
__global__ __launch_bounds__(256) void k_gemm(const float* __restrict__ A,
                                              const float* __restrict__ W,
                                              float* __restrict__ T, int nrows) {
  __shared__ float As[64 * DD];
  const int tid = threadIdx.x;
  const int cp  = tid & 63;
  const int rg  = tid >> 6;
  const long row0 = (long)blockIdx.x * 64;
  const int maxr = nrows - 1;

  #pragma unroll
  for (int j = 0; j < 8; ++j) {
    int idx4 = j * 256 + tid;
    int r = idx4 >> 5, k4 = idx4 & 31;
    long rr = row0 + r; if (rr > maxr) rr = maxr;
    ((float4*)As)[idx4] = ((const float4*)(A + rr * DD))[k4];
  }
  __syncthreads();

  float2 acc[16];
  #pragma unroll
  for (int r = 0; r < 16; ++r) acc[r] = make_float2(0.f, 0.f);

  const float* Abase = As + rg * 16 * DD;
  for (int k4 = 0; k4 < 32; ++k4) {
    float2 w[4];
    #pragma unroll
    for (int kk = 0; kk < 4; ++kk)
      w[kk] = ((const float2*)(W + (k4 * 4 + kk) * DD))[cp];
    #pragma unroll
    for (int r = 0; r < 16; ++r) {
      float4 a = *(const float4*)(Abase + r * DD + k4 * 4);
      acc[r].x += a.x * w[0].x + a.y * w[1].x + a.z * w[2].x + a.w * w[3].x;
      acc[r].y += a.x * w[0].y + a.y * w[1].y + a.z * w[2].y + a.w * w[3].y;
    }
  }

  #pragma unroll
  for (int r = 0; r < 16; ++r) {
    long rr = row0 + rg * 16 + r;
    if (rr < nrows) ((float2*)(T + rr * DD))[cp] = acc[r];
  }
}

// ---------------- fused node kernel: entity waves [0,N_ENT), user waves [N_ENT,NW) ----------------
__global__ __launch_bounds__(256) void k_node(const float* __restrict__ T,
                                              const float* __restrict__ ent,
                                              const float* __restrict__ rel,
                                              const int* __restrict__ packE,
                                              const int* __restrict__ startsE,
                                              const int* __restrict__ itemU,
                                              const float* __restrict__ wU,
                                              const int* __restrict__ startsU,
                                              float* __restrict__ next,
                                              float* __restrict__ resE,
                                              const float* __restrict__ resEInit,
                                              float* __restrict__ resU,
                                              const float* __restrict__ resUInit) {
  int w = (blockIdx.x * 256 + threadIdx.x) >> 6;
  int lane = threadIdx.x & 63;
  if (w >= NW) return;

  if (w < N_ENT) {
    // ---------------- entity path ----------------
    const int node = w;
    const int s0 = startsE[node], s1 = startsE[node + 1];
    float2 q = ((const float2*)(T + (long)node * DD))[lane];
    float m = -INFINITY, denom = 0.f;
    float2 acc = make_float2(0.f, 0.f);

    int p = s0;
    for (; p + 4 <= s1; p += 4) {
      int pk0 = packE[p], pk1 = packE[p + 1], pk2 = packE[p + 2], pk3 = packE[p + 3];
      long t0 = (long)(pk0 & 0xFFFFF) * DD, t1 = (long)(pk1 & 0xFFFFF) * DD;
      long t2 = (long)(pk2 & 0xFFFFF) * DD, t3 = (long)(pk3 & 0xFFFFF) * DD;
      float2 ra = ((const float2*)(rel + (pk0 >> 20) * DD))[lane];
      float2 rb = ((const float2*)(rel + (pk1 >> 20) * DD))[lane];
      float2 rc = ((const float2*)(rel + (pk2 >> 20) * DD))[lane];
      float2 rd = ((const float2*)(rel + (pk3 >> 20) * DD))[lane];
      float2 ta = ((const float2*)(T + t0))[lane];
      float2 tb = ((const float2*)(T + t1))[lane];
      float2 tc = ((const float2*)(T + t2))[lane];
      float2 td = ((const float2*)(T + t3))[lane];
      float2 va = ((const float2*)(ent + t0))[lane];
      float2 vb = ((const float2*)(ent + t1))[lane];
      float2 vc = ((const float2*)(ent + t2))[lane];
      float2 vd = ((const float2*)(ent + t3))[lane];

      float sA = q.x * ta.x * ra.x + q.y * ta.y * ra.y;
      float sB = q.x * tb.x * rb.x + q.y * tb.y * rb.y;
      float sC = q.x * tc.x * rc.x + q.y * tc.y * rc.y;
      float sD = q.x * td.x * rd.x + q.y * td.y * rd.y;
      #pragma unroll
      for (int off = 16; off; off >>= 1) {
        sA += __shfl_xor(sA, off, 32);
        sB += __shfl_xor(sB, off, 32);
        sC += __shfl_xor(sC, off, 32);
        sD += __shfl_xor(sD, off, 32);
      }
      sA *= 0.125f; sB *= 0.125f; sC *= 0.125f; sD *= 0.125f;

      float mb = fmaxf(fmaxf(sA, sB), fmaxf(sC, sD));
      float mn = fmaxf(m, mb);
      float c = __expf(m - mn);                 // m=-inf first batch -> c=0
      float eA = __expf(sA - mn), eB = __expf(sB - mn);
      float eC = __expf(sC - mn), eD = __expf(sD - mn);
      denom = denom * c + (eA + eB) + (eC + eD);
      acc.x = acc.x * c + va.x * ra.x * eA + vb.x * rb.x * eB + vc.x * rc.x * eC + vd.x * rd.x * eD;
      acc.y = acc.y * c + va.y * ra.y * eA + vb.y * rb.y * eB + vc.y * rc.y * eC + vd.y * rd.y * eD;
      m = mn;
    }
    for (; p < s1; ++p) {
      int pk = packE[p];
      long t0 = (long)(pk & 0xFFFFF) * DD;
      float2 r = ((const float2*)(rel + (pk >> 20) * DD))[lane];
      float2 t = ((const float2*)(T + t0))[lane];
      float2 v = ((const float2*)(ent + t0))[lane];
      float s = q.x * t.x * r.x + q.y * t.y * r.y;
      #pragma unroll
      for (int off = 16; off; off >>= 1) s += __shfl_xor(s, off, 32);
      s *= 0.125f;
      float mn = fmaxf(m, s);
      float c = __expf(m - mn);
      float ex = __expf(s - mn);
      denom = denom * c + ex;
      acc.x = acc.x * c + v.x * r.x * ex;
      acc.y = acc.y * c + v.y * r.y * ex;
      m = mn;
    }

    float inv_d = (s1 > s0) ? 1.0f / denom : 0.0f;   // deg==0 -> exact 0 row
    acc.x *= inv_d; acc.y *= inv_d;

    float ss = acc.x * acc.x + acc.y * acc.y;
    #pragma unroll
    for (int off = 32; off; off >>= 1) ss += __shfl_xor(ss, off);
    float inv = 1.0f / fmaxf(sqrtf(ss), 1e-12f);
    float2 nv = make_float2(acc.x * inv, acc.y * inv);

    if (next) ((float2*)(next + (long)node * DD))[lane] = nv;
    float2 base = resEInit ? ((const float2*)(resEInit + (long)node * DD))[lane]
                           : ((const float2*)(resE + (long)node * DD))[lane];
    base.x += nv.x; base.y += nv.y;
    ((float2*)(resE + (long)node * DD))[lane] = base;
  } else {
    // ---------------- user path ----------------
    const int u = w - N_ENT;
    const int s0 = startsU[u], s1 = startsU[u + 1];
    float2 acc = make_float2(0.f, 0.f);

    int p = s0;
    for (; p + 4 <= s1; p += 4) {
      int i0 = itemU[p], i1 = itemU[p + 1], i2 = itemU[p + 2], i3 = itemU[p + 3];
      float w0 = wU[p], w1 = wU[p + 1], w2 = wU[p + 2], w3 = wU[p + 3];
      float2 v0 = ((const float2*)(ent + (long)i0 * DD))[lane];
      float2 v1 = ((const float2*)(ent + (long)i1 * DD))[lane];
      float2 v2 = ((const float2*)(ent + (long)i2 * DD))[lane];
      float2 v3 = ((const float2*)(ent + (long)i3 * DD))[lane];
      acc.x += w0 * v0.x + w1 * v1.x + w2 * v2.x + w3 * v3.x;
      acc.y += w0 * v0.y + w1 * v1.y + w2 * v2.y + w3 * v3.y;
    }
    for (; p < s1; ++p) {
      int i0 = itemU[p];
      float w0 = wU[p];
      float2 v0 = ((const float2*)(ent + (long)i0 * DD))[lane];
      acc.x += w0 * v0.x; acc.y += w0 * v0.y;
    }

    float ss = acc.x * acc.x + acc.y * acc.y;
    #pragma unroll
    for (int off = 32; off; off >>= 1) ss += __shfl_xor(ss, off);
    float inv = 1.0f / fmaxf(sqrtf(ss), 1e-12f);   // ss==0 -> nv==0
    float2 nv = make_float2(acc.x * inv, acc.y * inv);

    float2 base = resUInit ? ((const float2*)(resUInit + (long)u * DD))[lane]
                           : ((const float2*)(resU + (long)u * DD))[lane];
    base.x += nv.x; base.y += nv.y;
    ((float2*)(resU + (long)u * DD))[lane] = base;
  }
}

extern "C" void kernel_launch(void* const* d_in, const int* in_sizes, int n_in,
                              void* d_out, int out_size, void* d_ws, size_t ws_size,
                              hipStream_t stream) {
  const float* user_emb   = (const float*)d_in[0];
  const float* entity_emb = (const float*)d_in[1];
  const float* W_Q        = (const float*)d_in[2];
  const float* rel_emb    = (const float*)d_in[3];
  const int*   edge_index = (const int*)d_in[4];
  const int*   edge_type  = (const int*)d_in[5];
  const int*   inter_edge = (const int*)d_in[6];
  const float* inter_w    = (const float*)d_in[7];

  float* out_user = (float*)d_out;                       // N_USR*DD
  float* out_ent  = out_user + (size_t)N_USR * DD;       // N_ENT*DD

  char* p = (char*)d_ws;
  float* bufT    = (float*)p; p += (size_t)N_ENT * DD * 4;   // T (per hop)
  float* bufN    = (float*)p; p += (size_t)N_ENT * DD * 4;   // normalized entities hop1
  int* degE      = (int*)p;   p += (size_t)N_ENT * 4;        // degE+degU contiguous (one memset)
  int* degU      = (int*)p;   p += (size_t)N_USR * 4;
  int* startsE   = (int*)p;   p += (size_t)(N_ENT + 1) * 4;
  int* startsU   = (int*)p;   p += (size_t)(N_USR + 1) * 4;
  int* cursorE   = (int*)p;   p += (size_t)N_ENT * 4;
  int* cursorU   = (int*)p;   p += (size_t)N_USR * 4;
  int* packE     = (int*)p;   p += (size_t)NE * 4;
  int* itemU     = (int*)p;   p += (size_t)NUI * 4;
  float* wUarr   = (float*)p; p += (size_t)NUI * 4;

  // ---- CSR build ----
  hipMemsetAsync(degE, 0, (size_t)(N_ENT + N_USR) * 4, stream);
  k_hist_all<<<(NE + NUI + 255) / 256, 256, 0, stream>>>(edge_index, inter_edge, degE, degU);
  k_scan2<<<2, 1024, 0, stream>>>(degE, startsE, cursorE, degU, startsU, cursorU);
  k_scatter_all<<<(NE + NUI + 255) / 256, 256, 0, stream>>>(edge_index, edge_type, inter_edge, inter_w,
                                                            cursorE, cursorU, packE, itemU, wUarr);

  // ---- hop 1 (residuals initialized from input embeddings inside k_node) ----
  k_gemm<<<(N_ENT + 63) / 64, 256, 0, stream>>>(entity_emb, W_Q, bufT, N_ENT);
  k_node<<<NW / 4, 256, 0, stream>>>(bufT, entity_emb, rel_emb,
                                     packE, startsE, itemU, wUarr, startsU,
                                     bufN, out_ent, entity_emb, out_user, user_emb);

  // ---- hop 2 ----
  k_gemm<<<(N_ENT + 63) / 64, 256, 0, stream>>>(bufN, W_Q, bufT, N_ENT);
  k_node<<<NW / 4, 256, 0, stream>>>(bufT, bufN, rel_emb,
                                     packE, startsE, itemU, wUarr, startsU,
                                     (float*)nullptr, out_ent, (const float*)nullptr,
                                     out_user, (const float*)nullptr);
}

// Round 6
// 694.720 us; speedup vs baseline: 3.6776x; 1.0862x over previous
//
#include <hip/hip_runtime.h>

#define N_ENT 100000
#define N_USR 50000
#define NE    600000
#define NUI   500000
#define DD    128
#define NW    (N_ENT + N_USR)

// ---------------- bf16 helpers (RNE pack, cheap unpack) ----------------
__device__ __forceinline__ unsigned bf16pack2(float a, float b) {
  unsigned ua = __float_as_uint(a); ua += 0x7FFF + ((ua >> 16) & 1);
  unsigned ub = __float_as_uint(b); ub += 0x7FFF + ((ub >> 16) & 1);
  return (ua >> 16) | (ub & 0xFFFF0000u);
}
__device__ __forceinline__ void bf2f8(uint4 u, float* f) {
  f[0] = __uint_as_float(u.x << 16); f[1] = __uint_as_float(u.x & 0xFFFF0000u);
  f[2] = __uint_as_float(u.y << 16); f[3] = __uint_as_float(u.y & 0xFFFF0000u);
  f[4] = __uint_as_float(u.z << 16); f[5] = __uint_as_float(u.z & 0xFFFF0000u);
  f[6] = __uint_as_float(u.w << 16); f[7] = __uint_as_float(u.w & 0xFFFF0000u);
}

// ---------------- histogram both edge sets ----------------
__global__ void k_hist_all(const int* __restrict__ ei, const int* __restrict__ ie,
                           int* __restrict__ degE, int* __restrict__ degU) {
  int i = blockIdx.x * 256 + threadIdx.x;
  if (i < NE) atomicAdd(&degE[ei[i]], 1);
  else if (i < NE + NUI) atomicAdd(&degU[ie[i - NE]], 1);
}

// ---------------- exclusive scan (2 blocks: ent, user); writes starts AND cursor ----------------
__global__ __launch_bounds__(1024) void k_scan2(const int* __restrict__ degE, int* __restrict__ startsE, int* __restrict__ cursorE,
                                                const int* __restrict__ degU, int* __restrict__ startsU, int* __restrict__ cursorU) {
  const int* deg = blockIdx.x ? degU : degE;
  int* starts    = blockIdx.x ? startsU : startsE;
  int* cursor    = blockIdx.x ? cursorU : cursorE;
  const int n    = blockIdx.x ? N_USR : N_ENT;

  __shared__ int wsum[16];
  __shared__ int carry;
  const int tid = threadIdx.x, lane = tid & 63, wid = tid >> 6;
  if (tid == 0) carry = 0;
  __syncthreads();

  for (int base = 0; base < n; base += 1024) {
    int i = base + tid;
    int v = (i < n) ? deg[i] : 0;
    int s = v;
    #pragma unroll
    for (int off = 1; off < 64; off <<= 1) {
      int t = __shfl_up(s, off, 64);
      if (lane >= off) s += t;
    }
    if (lane == 63) wsum[wid] = s;
    __syncthreads();
    if (wid == 0) {
      int ws = (lane < 16) ? wsum[lane] : 0;
      #pragma unroll
      for (int off = 1; off < 16; off <<= 1) {
        int t = __shfl_up(ws, off, 64);
        if (lane >= off) ws += t;
      }
      if (lane < 16) wsum[lane] = ws;
    }
    __syncthreads();
    int excl = carry + (wid ? wsum[wid - 1] : 0) + (s - v);
    if (i < n) { starts[i] = excl; cursor[i] = excl; }
    __syncthreads();
    if (tid == 0) carry += wsum[15];
    __syncthreads();
  }
  if (tid == 0) starts[n] = carry;
}

// ---------------- scatter payloads into CSR slot order ----------------
// entity edges: pack = tail | (rel_type << 20)  (tail < 2^17, rt < 9)
__global__ void k_scatter_all(const int* __restrict__ ei, const int* __restrict__ et,
                              const int* __restrict__ ie, const float* __restrict__ iw,
                              int* __restrict__ cursorE, int* __restrict__ cursorU,
                              int* __restrict__ packE, int* __restrict__ itemU, float* __restrict__ wU) {
  int i = blockIdx.x * 256 + threadIdx.x;
  if (i < NE) {
    int pos = atomicAdd(&cursorE[ei[i]], 1);
    packE[pos] = ei[NE + i] | (et[i] << 20);
  } else if (i < NE + NUI) {
    int j = i - NE;
    int pos = atomicAdd(&cursorU[ie[j]], 1);
    itemU[pos] = ie[NUI + j];
    wU[pos]    = iw[j];
  }
}

// ---------------- rel fp32 -> bf16 ----------------
__global__ void k_relcvt(const float* __restrict__ rel, unsigned* __restrict__ relB) {
  int u = blockIdx.x * 256 + threadIdx.x;
  if (u < 9 * 64) relB[u] = bf16pack2(rel[u * 2], rel[u * 2 + 1]);
}

// ---------------- T = A @ W ; emits bf16 T (+ optional bf16 mirror of A) ----------------
__global__ __launch_bounds__(256) void k_gemm(const float* __restrict__ A,
                                              const float* __restrict__ W,
                                              unsigned* __restrict__ Tb,
                                              unsigned* __restrict__ entB,   // may be null
                                              int nrows) {
  __shared__ float As[64 * DD];
  const int tid = threadIdx.x;
  const int cp  = tid & 63;
  const int rg  = tid >> 6;
  const long row0 = (long)blockIdx.x * 64;
  const int maxr = nrows - 1;

  #pragma unroll
  for (int j = 0; j < 8; ++j) {
    int idx4 = j * 256 + tid;
    int r = idx4 >> 5, k4 = idx4 & 31;
    long rr = row0 + r; if (rr > maxr) rr = maxr;
    ((float4*)As)[idx4] = ((const float4*)(A + rr * DD))[k4];
  }
  __syncthreads();

  if (entB) {   // bf16 mirror of the staged tile
    #pragma unroll
    for (int j = 0; j < 16; ++j) {
      int uidx = j * 256 + tid;             // < 4096
      int r = uidx >> 6, c2 = uidx & 63;
      long rr = row0 + r;
      if (rr < nrows)
        entB[rr * 64 + c2] = bf16pack2(As[r * DD + c2 * 2], As[r * DD + c2 * 2 + 1]);
    }
  }

  float2 acc[16];
  #pragma unroll
  for (int r = 0; r < 16; ++r) acc[r] = make_float2(0.f, 0.f);

  const float* Abase = As + rg * 16 * DD;
  for (int k4 = 0; k4 < 32; ++k4) {
    float2 w[4];
    #pragma unroll
    for (int kk = 0; kk < 4; ++kk)
      w[kk] = ((const float2*)(W + (k4 * 4 + kk) * DD))[cp];
    #pragma unroll
    for (int r = 0; r < 16; ++r) {
      float4 a = *(const float4*)(Abase + r * DD + k4 * 4);
      acc[r].x += a.x * w[0].x + a.y * w[1].x + a.z * w[2].x + a.w * w[3].x;
      acc[r].y += a.x * w[0].y + a.y * w[1].y + a.z * w[2].y + a.w * w[3].y;
    }
  }

  #pragma unroll
  for (int r = 0; r < 16; ++r) {
    long rr = row0 + rg * 16 + r;
    if (rr < nrows) Tb[rr * 64 + cp] = bf16pack2(acc[r].x, acc[r].y);
  }
}

// ---------------- fused node kernel (bf16 gathers, 16 lanes/row, 4 edges/wave) --------------
// wave w < N_ENT: entity node; else user u = w - N_ENT.
// lane = slot*16 + sub: slot = edge stream (0..3), sub = dim chunk (dims 8*sub..8*sub+7).
// head0 = sub 0..7, head1 = sub 8..15.
__global__ __launch_bounds__(256) void k_node(const unsigned* __restrict__ Tb,
                                              const unsigned* __restrict__ entB,
                                              const unsigned* __restrict__ relB,
                                              const int* __restrict__ packE,
                                              const int* __restrict__ startsE,
                                              const int* __restrict__ itemU,
                                              const float* __restrict__ wU,
                                              const int* __restrict__ startsU,
                                              float* __restrict__ next,        // fp32 bufN (null hop2)
                                              unsigned* __restrict__ entBout,  // bf16 mirror of next (null hop2)
                                              float* __restrict__ resE,
                                              const float* __restrict__ resEInit,
                                              float* __restrict__ resU,
                                              const float* __restrict__ resUInit) {
  const int w = (blockIdx.x * 256 + threadIdx.x) >> 6;
  const int lane = threadIdx.x & 63;
  const int slot = lane >> 4;
  const int sub  = lane & 15;
  if (w >= NW) return;

  if (w < N_ENT) {
    const int node = w;
    const int s0 = startsE[node], s1 = startsE[node + 1];

    float q[8];
    { uint4 qv = *(const uint4*)(Tb + (size_t)node * 64 + sub * 4); bf2f8(qv, q); }

    float acc[8];
    #pragma unroll
    for (int d = 0; d < 8; ++d) acc[d] = 0.f;
    float m = -1e30f, denom = 0.f;

    for (int p = s0; p < s1; p += 4) {
      int idx = p + slot;
      float vmask = (idx < s1) ? 1.f : 0.f;
      int ci = idx < NE ? idx : NE - 1;
      int pk = packE[ci];
      unsigned tail = (unsigned)(pk & 0xFFFFF); if (tail >= N_ENT) tail = N_ENT - 1;
      unsigned rt   = (unsigned)((pk >> 20) & 0xF); if (rt > 8) rt = 8;

      uint4 tb = *(const uint4*)(Tb   + (size_t)tail * 64 + sub * 4);
      uint4 vb = *(const uint4*)(entB + (size_t)tail * 64 + sub * 4);
      uint4 rb = *(const uint4*)(relB + (size_t)rt   * 64 + sub * 4);
      float tf[8], vf[8], rf[8];
      bf2f8(tb, tf); bf2f8(vb, vf); bf2f8(rb, rf);

      float s = 0.f;
      #pragma unroll
      for (int d = 0; d < 8; ++d) s += q[d] * (tf[d] * rf[d]);
      s += __shfl_xor(s, 1); s += __shfl_xor(s, 2); s += __shfl_xor(s, 4);
      s *= 0.125f;                                   // 1/sqrt(64)

      float mn = fmaxf(m, s);
      float c  = __expf(m - mn);                     // finite sentinel: never NaN
      float ex = __expf(s - mn) * vmask;
      denom = denom * c + ex;
      #pragma unroll
      for (int d = 0; d < 8; ++d) acc[d] = acc[d] * c + (vf[d] * rf[d]) * ex;
      m = mn;
    }

    // merge the 4 slot-streams (butterfly over lane bits 4,5)
    #pragma unroll
    for (int off = 16; off <= 32; off <<= 1) {
      float mo = __shfl_xor(m, off);
      float dn = __shfl_xor(denom, off);
      float mn = fmaxf(m, mo);
      float cs = __expf(m - mn), co = __expf(mo - mn);
      denom = denom * cs + dn * co;
      #pragma unroll
      for (int d = 0; d < 8; ++d) {
        float ao = __shfl_xor(acc[d], off);
        acc[d] = acc[d] * cs + ao * co;
      }
      m = mn;
    }

    float inv_d = (s1 > s0) ? 1.0f / denom : 0.0f;   // deg==0 -> exact 0 row
    float ss = 0.f;
    #pragma unroll
    for (int d = 0; d < 8; ++d) { acc[d] *= inv_d; ss += acc[d] * acc[d]; }
    ss += __shfl_xor(ss, 1); ss += __shfl_xor(ss, 2);
    ss += __shfl_xor(ss, 4); ss += __shfl_xor(ss, 8);
    float inv = 1.0f / fmaxf(sqrtf(ss), 1e-12f);
    #pragma unroll
    for (int d = 0; d < 8; ++d) acc[d] *= inv;

    if (slot == 0) {
      if (next) {
        float4* np = (float4*)(next + (size_t)node * DD + sub * 8);
        np[0] = make_float4(acc[0], acc[1], acc[2], acc[3]);
        np[1] = make_float4(acc[4], acc[5], acc[6], acc[7]);
        uint4 eb;
        eb.x = bf16pack2(acc[0], acc[1]); eb.y = bf16pack2(acc[2], acc[3]);
        eb.z = bf16pack2(acc[4], acc[5]); eb.w = bf16pack2(acc[6], acc[7]);
        *(uint4*)(entBout + (size_t)node * 64 + sub * 4) = eb;
      }
      const float* bs = resEInit ? resEInit : resE;
      float4 b0 = *(const float4*)(bs + (size_t)node * DD + sub * 8);
      float4 b1 = *(const float4*)(bs + (size_t)node * DD + sub * 8 + 4);
      b0.x += acc[0]; b0.y += acc[1]; b0.z += acc[2]; b0.w += acc[3];
      b1.x += acc[4]; b1.y += acc[5]; b1.z += acc[6]; b1.w += acc[7];
      ((float4*)(resE + (size_t)node * DD + sub * 8))[0] = b0;
      ((float4*)(resE + (size_t)node * DD + sub * 8 + 0))[1] = b1;
    }
  } else {
    const int u = w - N_ENT;
    const int s0 = startsU[u], s1 = startsU[u + 1];

    float acc[8];
    #pragma unroll
    for (int d = 0; d < 8; ++d) acc[d] = 0.f;

    for (int p = s0; p < s1; p += 4) {
      int idx = p + slot;
      float vmask = (idx < s1) ? 1.f : 0.f;
      int ci = idx < NUI ? idx : NUI - 1;
      unsigned it = (unsigned)itemU[ci]; if (it >= N_ENT) it = 0;
      float wt = wU[ci] * vmask;
      uint4 vb = *(const uint4*)(entB + (size_t)it * 64 + sub * 4);
      float vf[8]; bf2f8(vb, vf);
      #pragma unroll
      for (int d = 0; d < 8; ++d) acc[d] += wt * vf[d];
    }

    #pragma unroll
    for (int off = 16; off <= 32; off <<= 1) {
      #pragma unroll
      for (int d = 0; d < 8; ++d) acc[d] += __shfl_xor(acc[d], off);
    }

    float ss = 0.f;
    #pragma unroll
    for (int d = 0; d < 8; ++d) ss += acc[d] * acc[d];
    ss += __shfl_xor(ss, 1); ss += __shfl_xor(ss, 2);
    ss += __shfl_xor(ss, 4); ss += __shfl_xor(ss, 8);
    float inv = 1.0f / fmaxf(sqrtf(ss), 1e-12f);     // ss==0 -> 0 row
    #pragma unroll
    for (int d = 0; d < 8; ++d) acc[d] *= inv;

    if (slot == 0) {
      const float* bs = resUInit ? resUInit : resU;
      float4 b0 = *(const float4*)(bs + (size_t)u * DD + sub * 8);
      float4 b1 = *(const float4*)(bs + (size_t)u * DD + sub * 8 + 4);
      b0.x += acc[0]; b0.y += acc[1]; b0.z += acc[2]; b0.w += acc[3];
      b1.x += acc[4]; b1.y += acc[5]; b1.z += acc[6]; b1.w += acc[7];
      ((float4*)(resU + (size_t)u * DD + sub * 8))[0] = b0;
      *(float4*)(resU + (size_t)u * DD + sub * 8 + 4) = b1;
    }
  }
}

extern "C" void kernel_launch(void* const* d_in, const int* in_sizes, int n_in,
                              void* d_out, int out_size, void* d_ws, size_t ws_size,
                              hipStream_t stream) {
  const float* user_emb   = (const float*)d_in[0];
  const float* entity_emb = (const float*)d_in[1];
  const float* W_Q        = (const float*)d_in[2];
  const float* rel_emb    = (const float*)d_in[3];
  const int*   edge_index = (const int*)d_in[4];
  const int*   edge_type  = (const int*)d_in[5];
  const int*   inter_edge = (const int*)d_in[6];
  const float* inter_w    = (const float*)d_in[7];

  float* out_user = (float*)d_out;                       // N_USR*DD
  float* out_ent  = out_user + (size_t)N_USR * DD;       // N_ENT*DD

  char* p = (char*)d_ws;
  float*    bufN  = (float*)p;    p += (size_t)N_ENT * DD * 4;   // fp32 normalized (GEMM2 input)
  unsigned* Tb    = (unsigned*)p; p += (size_t)N_ENT * 64 * 4;   // bf16 T
  unsigned* entBa = (unsigned*)p; p += (size_t)N_ENT * 64 * 4;   // bf16 entities hop1
  unsigned* entBb = (unsigned*)p; p += (size_t)N_ENT * 64 * 4;   // bf16 entities hop2
  unsigned* relB  = (unsigned*)p; p += (size_t)9 * 64 * 4;
  int* degE      = (int*)p;   p += (size_t)N_ENT * 4;            // degE+degU contiguous
  int* degU      = (int*)p;   p += (size_t)N_USR * 4;
  int* startsE   = (int*)p;   p += (size_t)(N_ENT + 1) * 4;
  int* startsU   = (int*)p;   p += (size_t)(N_USR + 1) * 4;
  int* cursorE   = (int*)p;   p += (size_t)N_ENT * 4;
  int* cursorU   = (int*)p;   p += (size_t)N_USR * 4;
  int* packE     = (int*)p;   p += (size_t)NE * 4;
  int* itemU     = (int*)p;   p += (size_t)NUI * 4;
  float* wUarr   = (float*)p; p += (size_t)NUI * 4;

  // ---- CSR build ----
  hipMemsetAsync(degE, 0, (size_t)(N_ENT + N_USR) * 4, stream);
  k_hist_all<<<(NE + NUI + 255) / 256, 256, 0, stream>>>(edge_index, inter_edge, degE, degU);
  k_scan2<<<2, 1024, 0, stream>>>(degE, startsE, cursorE, degU, startsU, cursorU);
  k_scatter_all<<<(NE + NUI + 255) / 256, 256, 0, stream>>>(edge_index, edge_type, inter_edge, inter_w,
                                                            cursorE, cursorU, packE, itemU, wUarr);
  k_relcvt<<<3, 256, 0, stream>>>(rel_emb, relB);

  // ---- hop 1 ----
  k_gemm<<<(N_ENT + 63) / 64, 256, 0, stream>>>(entity_emb, W_Q, Tb, entBa, N_ENT);
  k_node<<<NW / 4, 256, 0, stream>>>(Tb, entBa, relB, packE, startsE, itemU, wUarr, startsU,
                                     bufN, entBb, out_ent, entity_emb, out_user, user_emb);

  // ---- hop 2 ----
  k_gemm<<<(N_ENT + 63) / 64, 256, 0, stream>>>(bufN, W_Q, Tb, (unsigned*)nullptr, N_ENT);
  k_node<<<NW / 4, 256, 0, stream>>>(Tb, entBb, relB, packE, startsE, itemU, wUarr, startsU,
                                     (float*)nullptr, (unsigned*)nullptr,
                                     out_ent, (const float*)nullptr,
                                     out_user, (const float*)nullptr);
}

// Round 9
// 640.675 us; speedup vs baseline: 3.9878x; 1.0844x over previous
//
#include <hip/hip_runtime.h>

#define N_ENT 100000
#define N_USR 50000
#define NE    600000
#define NUI   500000
#define DD    128
#define NW    (N_ENT + N_USR)

// Interleaved record per entity: 128 uints (512B) = [0..63] T-row bf16x2, [64..127] ent-row bf16x2.

// ---------------- bf16 helpers (RNE pack, cheap unpack) ----------------
__device__ __forceinline__ unsigned bf16pack2(float a, float b) {
  unsigned ua = __float_as_uint(a); ua += 0x7FFF + ((ua >> 16) & 1);
  unsigned ub = __float_as_uint(b); ub += 0x7FFF + ((ub >> 16) & 1);
  return (ua >> 16) | (ub & 0xFFFF0000u);
}
__device__ __forceinline__ void bf2f8(uint4 u, float* f) {
  f[0] = __uint_as_float(u.x << 16); f[1] = __uint_as_float(u.x & 0xFFFF0000u);
  f[2] = __uint_as_float(u.y << 16); f[3] = __uint_as_float(u.y & 0xFFFF0000u);
  f[4] = __uint_as_float(u.z << 16); f[5] = __uint_as_float(u.z & 0xFFFF0000u);
  f[6] = __uint_as_float(u.w << 16); f[7] = __uint_as_float(u.w & 0xFFFF0000u);
}

// ---------------- prep: degree histograms + entity fp32->bf16 (ent-half) + rel cvt ----------------
__global__ void k_prep(const int* __restrict__ ei, const int* __restrict__ ie,
                       int* __restrict__ degE, int* __restrict__ degU,
                       const float* __restrict__ ent, unsigned* __restrict__ IT1,
                       const float* __restrict__ rel, unsigned* __restrict__ relB) {
  int i = blockIdx.x * 256 + threadIdx.x;
  if (i < NE) atomicAdd(&degE[ei[i]], 1);
  else if (i < NE + NUI) atomicAdd(&degU[ie[i - NE]], 1);
  if (i < N_ENT * 16) {                       // one uint4 (8 dims) per thread
    int row = i >> 4, c4 = i & 15;
    const float4* src = (const float4*)(ent + (size_t)row * DD + c4 * 8);
    float4 a = src[0], b = src[1];
    uint4 u = make_uint4(bf16pack2(a.x, a.y), bf16pack2(a.z, a.w),
                         bf16pack2(b.x, b.y), bf16pack2(b.z, b.w));
    *(uint4*)(IT1 + (size_t)row * 128 + 64 + c4 * 4) = u;
  }
  if (i < 9 * 64) relB[i] = bf16pack2(rel[i * 2], rel[i * 2 + 1]);
}

// ---------------- exclusive scan (2 blocks: ent, user); writes starts AND cursor ----------------
__global__ __launch_bounds__(1024) void k_scan2(const int* __restrict__ degE, int* __restrict__ startsE, int* __restrict__ cursorE,
                                                const int* __restrict__ degU, int* __restrict__ startsU, int* __restrict__ cursorU) {
  const int* deg = blockIdx.x ? degU : degE;
  int* starts    = blockIdx.x ? startsU : startsE;
  int* cursor    = blockIdx.x ? cursorU : cursorE;
  const int n    = blockIdx.x ? N_USR : N_ENT;

  __shared__ int wsum[16];
  __shared__ int carry;
  const int tid = threadIdx.x, lane = tid & 63, wid = tid >> 6;
  if (tid == 0) carry = 0;
  __syncthreads();

  for (int base = 0; base < n; base += 1024) {
    int i = base + tid;
    int v = (i < n) ? deg[i] : 0;
    int s = v;
    #pragma unroll
    for (int off = 1; off < 64; off <<= 1) {
      int t = __shfl_up(s, off, 64);
      if (lane >= off) s += t;
    }
    if (lane == 63) wsum[wid] = s;
    __syncthreads();
    if (wid == 0) {
      int ws = (lane < 16) ? wsum[lane] : 0;
      #pragma unroll
      for (int off = 1; off < 16; off <<= 1) {
        int t = __shfl_up(ws, off, 64);
        if (lane >= off) ws += t;
      }
      if (lane < 16) wsum[lane] = ws;
    }
    __syncthreads();
    int excl = carry + (wid ? wsum[wid - 1] : 0) + (s - v);
    if (i < n) { starts[i] = excl; cursor[i] = excl; }
    __syncthreads();
    if (tid == 0) carry += wsum[15];
    __syncthreads();
  }
  if (tid == 0) starts[n] = carry;
}

// ---------------- scatter payloads into CSR slot order ----------------
__global__ void k_scatter_all(const int* __restrict__ ei, const int* __restrict__ et,
                              const int* __restrict__ ie, const float* __restrict__ iw,
                              int* __restrict__ cursorE, int* __restrict__ cursorU,
                              int* __restrict__ packE, int* __restrict__ itemU, float* __restrict__ wU) {
  int i = blockIdx.x * 256 + threadIdx.x;
  if (i < NE) {
    int pos = atomicAdd(&cursorE[ei[i]], 1);
    packE[pos] = ei[NE + i] | (et[i] << 20);
  } else if (i < NE + NUI) {
    int j = i - NE;
    int pos = atomicAdd(&cursorU[ie[j]], 1);
    itemU[pos] = ie[NUI + j];
    wU[pos]    = iw[j];
  }
}

// ---------------- T-half = bf16( ent-half @ W ) within the interleaved buffer ----------------
__global__ __launch_bounds__(256) void k_gemm(unsigned* __restrict__ IT,
                                              const float* __restrict__ W) {
  __shared__ float As[64 * DD];
  const int tid = threadIdx.x;
  const int cp  = tid & 63;
  const int rg  = tid >> 6;
  const long row0 = (long)blockIdx.x * 64;
  const int maxr = N_ENT - 1;

  #pragma unroll
  for (int j = 0; j < 4; ++j) {            // stage 64 rows from bf16 ent-half, unpacked to fp32
    int idx4 = j * 256 + tid;              // < 1024
    int r = idx4 >> 4, c4 = idx4 & 15;
    long rr = row0 + r; if (rr > maxr) rr = maxr;
    uint4 u = *(const uint4*)(IT + rr * 128 + 64 + c4 * 4);
    float f[8]; bf2f8(u, f);
    float4* d = (float4*)(As + r * DD + c4 * 8);
    d[0] = make_float4(f[0], f[1], f[2], f[3]);
    d[1] = make_float4(f[4], f[5], f[6], f[7]);
  }
  __syncthreads();

  float2 acc[16];
  #pragma unroll
  for (int r = 0; r < 16; ++r) acc[r] = make_float2(0.f, 0.f);

  const float* Abase = As + rg * 16 * DD;
  for (int k4 = 0; k4 < 32; ++k4) {
    float2 w[4];
    #pragma unroll
    for (int kk = 0; kk < 4; ++kk)
      w[kk] = ((const float2*)(W + (k4 * 4 + kk) * DD))[cp];
    #pragma unroll
    for (int r = 0; r < 16; ++r) {
      float4 a = *(const float4*)(Abase + r * DD + k4 * 4);   // wave-uniform broadcast
      acc[r].x += a.x * w[0].x + a.y * w[1].x + a.z * w[2].x + a.w * w[3].x;
      acc[r].y += a.x * w[0].y + a.y * w[1].y + a.z * w[2].y + a.w * w[3].y;
    }
  }

  #pragma unroll
  for (int r = 0; r < 16; ++r) {
    long rr = row0 + rg * 16 + r;
    if (rr <= maxr) IT[rr * 128 + cp] = bf16pack2(acc[r].x, acc[r].y);
  }
}

// ---------------- fused node kernel: no-max softmax, interleaved 512B gathers ----------------
// wave w < N_ENT: entity; else user. lane = slot*16 + sub (slot: edge stream, sub: dim chunk).
__global__ __launch_bounds__(256) void k_node(const unsigned* __restrict__ IT,
                                              const unsigned* __restrict__ relB,
                                              const int* __restrict__ packE,
                                              const int* __restrict__ startsE,
                                              const int* __restrict__ itemU,
                                              const float* __restrict__ wU,
                                              const int* __restrict__ startsU,
                                              unsigned* __restrict__ ITout,    // null on hop2
                                              float* __restrict__ resE, const float* __restrict__ resEInit,
                                              float* __restrict__ resU, const float* __restrict__ resUInit) {
  const int w = (blockIdx.x * 256 + threadIdx.x) >> 6;
  const int lane = threadIdx.x & 63;
  const int slot = lane >> 4;
  const int sub  = lane & 15;
  if (w >= NW) return;

  if (w < N_ENT) {
    const int node = w;
    const int s0 = startsE[node], s1 = startsE[node + 1];

    float q[8];
    { uint4 qv = *(const uint4*)(IT + (size_t)node * 128 + sub * 4); bf2f8(qv, q); }

    float acc[8];
    #pragma unroll
    for (int d = 0; d < 8; ++d) acc[d] = 0.f;
    float denom = 0.f;

    // software-pipelined packE load (hide index->gather chain)
    int pk = (s1 > s0) ? packE[(s0 + slot < s1) ? s0 + slot : s0] : 0;

    for (int p = s0; p < s1; p += 4) {
      int curidx = p + slot;
      float vmask = (curidx < s1) ? 1.f : 0.f;
      int pkc = pk;
      if (p + 4 < s1) {                      // prefetch next batch's pack
        int nidx = curidx + 4;
        pk = packE[nidx < s1 ? nidx : s0];
      }
      unsigned tail = (unsigned)(pkc & 0xFFFFF); if (tail >= N_ENT) tail = 0;
      unsigned rt   = (unsigned)((pkc >> 20) & 0xF); if (rt > 8) rt = 8;

      const unsigned* rowp = IT + (size_t)tail * 128;
      uint4 tb = *(const uint4*)(rowp + sub * 4);         // T-row chunk
      uint4 vb = *(const uint4*)(rowp + 64 + sub * 4);    // ent-row chunk (adjacent 256B)
      uint4 rb = *(const uint4*)(relB + rt * 64 + sub * 4);
      float tf[8], vf[8], rf[8];
      bf2f8(tb, tf); bf2f8(vb, vf); bf2f8(rb, rf);

      float s = 0.f;
      #pragma unroll
      for (int d = 0; d < 8; ++d) s += q[d] * (tf[d] * rf[d]);
      s += __shfl_xor(s, 1); s += __shfl_xor(s, 2); s += __shfl_xor(s, 4);
      // scores ~N(0,~1.5): exp without max-subtraction is exact softmax math; clamp for safety
      float ex = __expf(fminf(s * 0.125f, 60.f)) * vmask;
      denom += ex;
      #pragma unroll
      for (int d = 0; d < 8; ++d) acc[d] += (vf[d] * rf[d]) * ex;
    }

    // merge 4 slot-streams: plain sums
    #pragma unroll
    for (int off = 16; off <= 32; off <<= 1) {
      denom += __shfl_xor(denom, off);
      #pragma unroll
      for (int d = 0; d < 8; ++d) acc[d] += __shfl_xor(acc[d], off);
    }

    float inv_d = (s1 > s0) ? 1.0f / denom : 0.0f;   // deg==0 -> exact 0 row
    float ss = 0.f;
    #pragma unroll
    for (int d = 0; d < 8; ++d) { acc[d] *= inv_d; ss += acc[d] * acc[d]; }
    ss += __shfl_xor(ss, 1); ss += __shfl_xor(ss, 2);
    ss += __shfl_xor(ss, 4); ss += __shfl_xor(ss, 8);
    float inv = 1.0f / fmaxf(sqrtf(ss), 1e-12f);
    #pragma unroll
    for (int d = 0; d < 8; ++d) acc[d] *= inv;

    if (slot == 0) {
      if (ITout) {
        uint4 eb = make_uint4(bf16pack2(acc[0], acc[1]), bf16pack2(acc[2], acc[3]),
                              bf16pack2(acc[4], acc[5]), bf16pack2(acc[6], acc[7]));
        *(uint4*)(ITout + (size_t)node * 128 + 64 + sub * 4) = eb;
      }
      const float* bs = resEInit ? resEInit : resE;
      float4 b0 = ((const float4*)(bs + (size_t)node * DD))[sub * 2];
      float4 b1 = ((const float4*)(bs + (size_t)node * DD))[sub * 2 + 1];
      b0.x += acc[0]; b0.y += acc[1]; b0.z += acc[2]; b0.w += acc[3];
      b1.x += acc[4]; b1.y += acc[5]; b1.z += acc[6]; b1.w += acc[7];
      ((float4*)(resE + (size_t)node * DD))[sub * 2]     = b0;
      ((float4*)(resE + (size_t)node * DD))[sub * 2 + 1] = b1;
    }
  } else {
    const int u = w - N_ENT;
    const int s0 = startsU[u], s1 = startsU[u + 1];

    float acc[8];
    #pragma unroll
    for (int d = 0; d < 8; ++d) acc[d] = 0.f;

    for (int p = s0; p < s1; p += 4) {
      int idx = p + slot;
      float vmask = (idx < s1) ? 1.f : 0.f;
      int ci = idx < s1 ? idx : s0;
      unsigned it = (unsigned)itemU[ci]; if (it >= N_ENT) it = 0;
      float wt = wU[ci] * vmask;
      uint4 vb = *(const uint4*)(IT + (size_t)it * 128 + 64 + sub * 4);  // ent-half
      float vf[8]; bf2f8(vb, vf);
      #pragma unroll
      for (int d = 0; d < 8; ++d) acc[d] += wt * vf[d];
    }

    #pragma unroll
    for (int off = 16; off <= 32; off <<= 1) {
      #pragma unroll
      for (int d = 0; d < 8; ++d) acc[d] += __shfl_xor(acc[d], off);
    }

    float ss = 0.f;
    #pragma unroll
    for (int d = 0; d < 8; ++d) ss += acc[d] * acc[d];
    ss += __shfl_xor(ss, 1); ss += __shfl_xor(ss, 2);
    ss += __shfl_xor(ss, 4); ss += __shfl_xor(ss, 8);
    float inv = 1.0f / fmaxf(sqrtf(ss), 1e-12f);     // ss==0 -> 0 row
    #pragma unroll
    for (int d = 0; d < 8; ++d) acc[d] *= inv;

    if (slot == 0) {
      const float* bs = resUInit ? resUInit : resU;
      float4 b0 = ((const float4*)(bs + (size_t)u * DD))[sub * 2];
      float4 b1 = ((const float4*)(bs + (size_t)u * DD))[sub * 2 + 1];
      b0.x += acc[0]; b0.y += acc[1]; b0.z += acc[2]; b0.w += acc[3];
      b1.x += acc[4]; b1.y += acc[5]; b1.z += acc[6]; b1.w += acc[7];
      ((float4*)(resU + (size_t)u * DD))[sub * 2]     = b0;
      ((float4*)(resU + (size_t)u * DD))[sub * 2 + 1] = b1;
    }
  }
}

extern "C" void kernel_launch(void* const* d_in, const int* in_sizes, int n_in,
                              void* d_out, int out_size, void* d_ws, size_t ws_size,
                              hipStream_t stream) {
  const float* user_emb   = (const float*)d_in[0];
  const float* entity_emb = (const float*)d_in[1];
  const float* W_Q        = (const float*)d_in[2];
  const float* rel_emb    = (const float*)d_in[3];
  const int*   edge_index = (const int*)d_in[4];
  const int*   edge_type  = (const int*)d_in[5];
  const int*   inter_edge = (const int*)d_in[6];
  const float* inter_w    = (const float*)d_in[7];

  float* out_user = (float*)d_out;                       // N_USR*DD
  float* out_ent  = out_user + (size_t)N_USR * DD;       // N_ENT*DD

  char* p = (char*)d_ws;
  unsigned* IT1   = (unsigned*)p; p += (size_t)N_ENT * 128 * 4;  // hop1 interleaved T|ent
  unsigned* IT2   = (unsigned*)p; p += (size_t)N_ENT * 128 * 4;  // hop2 interleaved T|ent
  unsigned* relB  = (unsigned*)p; p += (size_t)9 * 64 * 4;
  int* degE      = (int*)p;   p += (size_t)N_ENT * 4;            // degE+degU contiguous
  int* degU      = (int*)p;   p += (size_t)N_USR * 4;
  int* startsE   = (int*)p;   p += (size_t)(N_ENT + 1) * 4;
  int* startsU   = (int*)p;   p += (size_t)(N_USR + 1) * 4;
  int* cursorE   = (int*)p;   p += (size_t)N_ENT * 4;
  int* cursorU   = (int*)p;   p += (size_t)N_USR * 4;
  int* packE     = (int*)p;   p += (size_t)NE * 4;
  int* itemU     = (int*)p;   p += (size_t)NUI * 4;
  float* wUarr   = (float*)p; p += (size_t)NUI * 4;

  // ---- CSR build + bf16 conversions ----
  hipMemsetAsync(degE, 0, (size_t)(N_ENT + N_USR) * 4, stream);
  k_prep<<<(N_ENT * 16 + 255) / 256, 256, 0, stream>>>(edge_index, inter_edge, degE, degU,
                                                       entity_emb, IT1, rel_emb, relB);
  k_scan2<<<2, 1024, 0, stream>>>(degE, startsE, cursorE, degU, startsU, cursorU);
  k_scatter_all<<<(NE + NUI + 255) / 256, 256, 0, stream>>>(edge_index, edge_type, inter_edge, inter_w,
                                                            cursorE, cursorU, packE, itemU, wUarr);

  // ---- hop 1 ----
  k_gemm<<<(N_ENT + 63) / 64, 256, 0, stream>>>(IT1, W_Q);
  k_node<<<NW / 4, 256, 0, stream>>>(IT1, relB, packE, startsE, itemU, wUarr, startsU,
                                     IT2, out_ent, entity_emb, out_user, user_emb);

  // ---- hop 2 ----
  k_gemm<<<(N_ENT + 63) / 64, 256, 0, stream>>>(IT2, W_Q);
  k_node<<<NW / 4, 256, 0, stream>>>(IT2, relB, packE, startsE, itemU, wUarr, startsU,
                                     (unsigned*)nullptr, out_ent, (const float*)nullptr,
                                     out_user, (const float*)nullptr);
}

// Round 10
// 480.351 us; speedup vs baseline: 5.3188x; 1.3338x over previous
//
#include <hip/hip_runtime.h>

#define N_ENT 100000
#define N_USR 50000
#define NE    600000
#define NUI   500000
#define DD    128
#define NW    (N_ENT + N_USR)
#define NBLK_E 98              // ceil(100000/1024)
#define NBLK_U 49              // ceil(50000/1024)
#define NBLK_SCAN (NBLK_E + NBLK_U)

typedef __attribute__((ext_vector_type(8))) short short8v;   // 8 bf16 (4 VGPRs)
typedef __attribute__((ext_vector_type(4))) float f32x4;

// Interleaved record per entity: 128 uints (512B) = [0..63] T-row bf16x2, [64..127] ent-row bf16x2.

// ---------------- bf16 helpers ----------------
__device__ __forceinline__ unsigned bf16pack2(float a, float b) {
  unsigned ua = __float_as_uint(a); ua += 0x7FFF + ((ua >> 16) & 1);
  unsigned ub = __float_as_uint(b); ub += 0x7FFF + ((ub >> 16) & 1);
  return (ua >> 16) | (ub & 0xFFFF0000u);
}
__device__ __forceinline__ void bf2f8(uint4 u, float* f) {
  f[0] = __uint_as_float(u.x << 16); f[1] = __uint_as_float(u.x & 0xFFFF0000u);
  f[2] = __uint_as_float(u.y << 16); f[3] = __uint_as_float(u.y & 0xFFFF0000u);
  f[4] = __uint_as_float(u.z << 16); f[5] = __uint_as_float(u.z & 0xFFFF0000u);
  f[6] = __uint_as_float(u.w << 16); f[7] = __uint_as_float(u.w & 0xFFFF0000u);
}
__device__ __forceinline__ unsigned cvt_pk_bf16(float lo, float hi) {
  unsigned r;
  asm volatile("v_cvt_pk_bf16_f32 %0, %1, %2" : "=v"(r) : "v"(lo), "v"(hi));
  return r;
}

// ---------------- prep: histograms + ent->bf16 + rel cvt + W fragment pack ----------------
// Wp layout: j in [0,2048): lane=j&63, cf=(j>>6)&7, ks=j>>9.
// Wp[j] = uint4 of 8 bf16 = W[k][col], col=cf*16+(lane&15), k=ks*32+((lane>>4)&3)*8 + 0..7.
__global__ void k_prep(const int* __restrict__ ei, const int* __restrict__ ie,
                       int* __restrict__ degE, int* __restrict__ degU,
                       const float* __restrict__ ent, unsigned* __restrict__ IT1,
                       const float* __restrict__ rel, unsigned* __restrict__ relB,
                       const float* __restrict__ W, uint4* __restrict__ Wp) {
  int i = blockIdx.x * 256 + threadIdx.x;
  if (i < NE) atomicAdd(&degE[ei[i]], 1);
  else if (i < NE + NUI) atomicAdd(&degU[ie[i - NE]], 1);
  if (i < N_ENT * 16) {                       // one uint4 (8 dims) per thread
    int row = i >> 4, c4 = i & 15;
    const float4* src = (const float4*)(ent + (size_t)row * DD + c4 * 8);
    float4 a = src[0], b = src[1];
    uint4 u = make_uint4(bf16pack2(a.x, a.y), bf16pack2(a.z, a.w),
                         bf16pack2(b.x, b.y), bf16pack2(b.z, b.w));
    *(uint4*)(IT1 + (size_t)row * 128 + 64 + c4 * 4) = u;
  }
  if (i < 9 * 64) relB[i] = bf16pack2(rel[i * 2], rel[i * 2 + 1]);
  if (i < 2048) {
    int lane = i & 63, cf = (i >> 6) & 7, ks = i >> 9;
    int col = cf * 16 + (lane & 15);
    int kb  = ks * 32 + ((lane >> 4) & 3) * 8;
    uint4 u;
    u.x = bf16pack2(W[(kb + 0) * DD + col], W[(kb + 1) * DD + col]);
    u.y = bf16pack2(W[(kb + 2) * DD + col], W[(kb + 3) * DD + col]);
    u.z = bf16pack2(W[(kb + 4) * DD + col], W[(kb + 5) * DD + col]);
    u.w = bf16pack2(W[(kb + 6) * DD + col], W[(kb + 7) * DD + col]);
    Wp[i] = u;
  }
}

// ---------------- scan phase A: per-block local exclusive scan (1024 elems/block) ----------------
__global__ __launch_bounds__(256) void k_scanA(const int* __restrict__ degE, const int* __restrict__ degU,
                                               int* __restrict__ startsE, int* __restrict__ startsU,
                                               int* __restrict__ blkSum) {
  int bid = blockIdx.x;
  const int* src; int* loc; int n, base;
  if (bid < NBLK_E) { src = degE; loc = startsE; n = N_ENT; base = bid * 1024; }
  else              { src = degU; loc = startsU; n = N_USR; base = (bid - NBLK_E) * 1024; }
  int tid = threadIdx.x, lane = tid & 63, wid = tid >> 6;
  int i0 = base + tid * 4;
  int4 v = make_int4(0, 0, 0, 0);
  if (i0 + 3 < n) v = *(const int4*)(src + i0);
  else {
    if (i0     < n) v.x = src[i0];
    if (i0 + 1 < n) v.y = src[i0 + 1];
    if (i0 + 2 < n) v.z = src[i0 + 2];
    if (i0 + 3 < n) v.w = src[i0 + 3];
  }
  int tsum = v.x + v.y + v.z + v.w;
  int s = tsum;
  #pragma unroll
  for (int off = 1; off < 64; off <<= 1) {
    int t = __shfl_up(s, off, 64);
    if (lane >= off) s += t;
  }
  __shared__ int ws[4];
  if (lane == 63) ws[wid] = s;
  __syncthreads();
  int woff = 0;
  #pragma unroll
  for (int k = 0; k < 4; ++k) if (k < wid) woff += ws[k];
  int excl = woff + s - tsum;
  if (i0     < n) loc[i0]     = excl;
  if (i0 + 1 < n) loc[i0 + 1] = excl + v.x;
  if (i0 + 2 < n) loc[i0 + 2] = excl + v.x + v.y;
  if (i0 + 3 < n) loc[i0 + 3] = excl + v.x + v.y + v.z;
  if (tid == 255) blkSum[bid] = woff + s;
}

// ---------------- scan phase B: scan the block sums (wave0: E, wave1: U) ----------------
__global__ __launch_bounds__(256) void k_scanB(const int* __restrict__ blkSum, int* __restrict__ blkOff,
                                               int* __restrict__ startsE, int* __restrict__ startsU) {
  int tid = threadIdx.x, lane = tid & 63, wid = tid >> 6;
  if (wid > 1) return;
  int base = wid ? NBLK_E : 0;
  int m    = wid ? NBLK_U : NBLK_E;
  int a = (2 * lane     < m) ? blkSum[base + 2 * lane]     : 0;
  int b = (2 * lane + 1 < m) ? blkSum[base + 2 * lane + 1] : 0;
  int ps = a + b;
  #pragma unroll
  for (int off = 1; off < 64; off <<= 1) {
    int t = __shfl_up(ps, off, 64);
    if (lane >= off) ps += t;
  }
  int excl = ps - (a + b);
  if (2 * lane     < m) blkOff[base + 2 * lane]     = excl;
  if (2 * lane + 1 < m) blkOff[base + 2 * lane + 1] = excl + a;
  if (lane == 63) { if (wid) startsU[N_USR] = ps; else startsE[N_ENT] = ps; }
}

// ---------------- scan phase C: apply block offsets, write cursor ----------------
__global__ __launch_bounds__(256) void k_scanC(int* __restrict__ startsE, int* __restrict__ startsU,
                                               int* __restrict__ cursorE, int* __restrict__ cursorU,
                                               const int* __restrict__ blkOff) {
  int bid = blockIdx.x;
  int* st; int* cu; int n, base;
  if (bid < NBLK_E) { st = startsE; cu = cursorE; n = N_ENT; base = bid * 1024; }
  else              { st = startsU; cu = cursorU; n = N_USR; base = (bid - NBLK_E) * 1024; }
  int off = blkOff[bid];
  int i0 = base + threadIdx.x * 4;
  if (i0 + 3 < n) {
    int4 v = *(const int4*)(st + i0);
    v.x += off; v.y += off; v.z += off; v.w += off;
    *(int4*)(st + i0) = v;
    *(int4*)(cu + i0) = v;
  } else {
    for (int k = 0; k < 4; ++k)
      if (i0 + k < n) { int v = st[i0 + k] + off; st[i0 + k] = v; cu[i0 + k] = v; }
  }
}

// ---------------- scatter payloads into CSR slot order ----------------
__global__ void k_scatter_all(const int* __restrict__ ei, const int* __restrict__ et,
                              const int* __restrict__ ie, const float* __restrict__ iw,
                              int* __restrict__ cursorE, int* __restrict__ cursorU,
                              int* __restrict__ packE, int* __restrict__ itemU, float* __restrict__ wU) {
  int i = blockIdx.x * 256 + threadIdx.x;
  if (i < NE) {
    int pos = atomicAdd(&cursorE[ei[i]], 1);
    packE[pos] = ei[NE + i] | (et[i] << 20);
  } else if (i < NE + NUI) {
    int j = i - NE;
    int pos = atomicAdd(&cursorU[ie[j]], 1);
    itemU[pos] = ie[NUI + j];
    wU[pos]    = iw[j];
  }
}

// ---------------- MFMA GEMM: T-half = bf16( ent-half @ W ), per-wave 16 rows x 128 cols ----------
__global__ __launch_bounds__(256) void k_gemm(unsigned* __restrict__ IT, const uint4* __restrict__ Wp) {
  const int tid  = threadIdx.x;
  const int lane = tid & 63;
  const int wave = tid >> 6;
  const int row0 = blockIdx.x * 64 + wave * 16;       // wave's 16 output rows
  const int kc   = lane >> 4;                          // k-chunk 0..3
  int rowA = row0 + (lane & 15);                       // A-fragment row
  if (rowA > N_ENT - 1) rowA = N_ENT - 1;
  const unsigned* Arow = IT + (size_t)rowA * 128 + 64; // ent-half

  f32x4 c[8];
  #pragma unroll
  for (int cf = 0; cf < 8; ++cf) c[cf] = (f32x4){0.f, 0.f, 0.f, 0.f};

  #pragma unroll
  for (int ks = 0; ks < 4; ++ks) {
    short8v a = *(const short8v*)(Arow + ks * 16 + kc * 4);   // A[row][k=ks*32+kc*8..+8]
    #pragma unroll
    for (int cf = 0; cf < 8; ++cf) {
      short8v b = *(const short8v*)(&Wp[(ks * 8 + cf) * 64 + lane]);
      c[cf] = __builtin_amdgcn_mfma_f32_16x16x32_bf16(a, b, c[cf], 0, 0, 0);
    }
  }

  // C layout: col = lane&15 (+cf*16), row = (lane>>4)*4 + reg. Pack col pairs via lane^1.
  #pragma unroll
  for (int cf = 0; cf < 8; ++cf) {
    #pragma unroll
    for (int reg = 0; reg < 4; ++reg) {
      float me = c[cf][reg];
      float nb = __shfl_xor(me, 1);
      if (!(lane & 1)) {
        int rowg = row0 + (lane >> 4) * 4 + reg;
        if (rowg < N_ENT)
          IT[(size_t)rowg * 128 + cf * 8 + ((lane & 15) >> 1)] = cvt_pk_bf16(me, nb);
      }
    }
  }
}

// ---------------- fused node kernel: no-max softmax, interleaved 512B gathers ----------------
// wave w < N_ENT: entity; else user. lane = slot*16 + sub (slot: edge stream, sub: dim chunk).
__global__ __launch_bounds__(256) void k_node(const unsigned* __restrict__ IT,
                                              const unsigned* __restrict__ relB,
                                              const int* __restrict__ packE,
                                              const int* __restrict__ startsE,
                                              const int* __restrict__ itemU,
                                              const float* __restrict__ wU,
                                              const int* __restrict__ startsU,
                                              unsigned* __restrict__ ITout,    // null on hop2
                                              float* __restrict__ resE, const float* __restrict__ resEInit,
                                              float* __restrict__ resU, const float* __restrict__ resUInit) {
  const int w = (blockIdx.x * 256 + threadIdx.x) >> 6;
  const int lane = threadIdx.x & 63;
  const int slot = lane >> 4;
  const int sub  = lane & 15;
  if (w >= NW) return;

  if (w < N_ENT) {
    const int node = w;
    const int s0 = startsE[node], s1 = startsE[node + 1];

    float q[8];
    { uint4 qv = *(const uint4*)(IT + (size_t)node * 128 + sub * 4); bf2f8(qv, q); }

    float acc[8];
    #pragma unroll
    for (int d = 0; d < 8; ++d) acc[d] = 0.f;
    float denom = 0.f;

    int pk = (s1 > s0) ? packE[(s0 + slot < s1) ? s0 + slot : s0] : 0;

    for (int p = s0; p < s1; p += 4) {
      int curidx = p + slot;
      float vmask = (curidx < s1) ? 1.f : 0.f;
      int pkc = pk;
      if (p + 4 < s1) {
        int nidx = curidx + 4;
        pk = packE[nidx < s1 ? nidx : s0];
      }
      unsigned tail = (unsigned)(pkc & 0xFFFFF); if (tail >= N_ENT) tail = 0;
      unsigned rt   = (unsigned)((pkc >> 20) & 0xF); if (rt > 8) rt = 8;

      const unsigned* rowp = IT + (size_t)tail * 128;
      uint4 tb = *(const uint4*)(rowp + sub * 4);
      uint4 vb = *(const uint4*)(rowp + 64 + sub * 4);
      uint4 rb = *(const uint4*)(relB + rt * 64 + sub * 4);
      float tf[8], vf[8], rf[8];
      bf2f8(tb, tf); bf2f8(vb, vf); bf2f8(rb, rf);

      float s = 0.f;
      #pragma unroll
      for (int d = 0; d < 8; ++d) s += q[d] * (tf[d] * rf[d]);
      s += __shfl_xor(s, 1); s += __shfl_xor(s, 2); s += __shfl_xor(s, 4);
      float ex = __expf(fminf(s * 0.125f, 60.f)) * vmask;
      denom += ex;
      #pragma unroll
      for (int d = 0; d < 8; ++d) acc[d] += (vf[d] * rf[d]) * ex;
    }

    #pragma unroll
    for (int off = 16; off <= 32; off <<= 1) {
      denom += __shfl_xor(denom, off);
      #pragma unroll
      for (int d = 0; d < 8; ++d) acc[d] += __shfl_xor(acc[d], off);
    }

    float inv_d = (s1 > s0) ? 1.0f / denom : 0.0f;
    float ss = 0.f;
    #pragma unroll
    for (int d = 0; d < 8; ++d) { acc[d] *= inv_d; ss += acc[d] * acc[d]; }
    ss += __shfl_xor(ss, 1); ss += __shfl_xor(ss, 2);
    ss += __shfl_xor(ss, 4); ss += __shfl_xor(ss, 8);
    float inv = 1.0f / fmaxf(sqrtf(ss), 1e-12f);
    #pragma unroll
    for (int d = 0; d < 8; ++d) acc[d] *= inv;

    if (slot == 0) {
      if (ITout) {
        uint4 eb = make_uint4(bf16pack2(acc[0], acc[1]), bf16pack2(acc[2], acc[3]),
                              bf16pack2(acc[4], acc[5]), bf16pack2(acc[6], acc[7]));
        *(uint4*)(ITout + (size_t)node * 128 + 64 + sub * 4) = eb;
      }
      const float* bs = resEInit ? resEInit : resE;
      float4 b0 = ((const float4*)(bs + (size_t)node * DD))[sub * 2];
      float4 b1 = ((const float4*)(bs + (size_t)node * DD))[sub * 2 + 1];
      b0.x += acc[0]; b0.y += acc[1]; b0.z += acc[2]; b0.w += acc[3];
      b1.x += acc[4]; b1.y += acc[5]; b1.z += acc[6]; b1.w += acc[7];
      ((float4*)(resE + (size_t)node * DD))[sub * 2]     = b0;
      ((float4*)(resE + (size_t)node * DD))[sub * 2 + 1] = b1;
    }
  } else {
    const int u = w - N_ENT;
    const int s0 = startsU[u], s1 = startsU[u + 1];

    float acc[8];
    #pragma unroll
    for (int d = 0; d < 8; ++d) acc[d] = 0.f;

    for (int p = s0; p < s1; p += 4) {
      int idx = p + slot;
      float vmask = (idx < s1) ? 1.f : 0.f;
      int ci = idx < s1 ? idx : s0;
      unsigned it = (unsigned)itemU[ci]; if (it >= N_ENT) it = 0;
      float wt = wU[ci] * vmask;
      uint4 vb = *(const uint4*)(IT + (size_t)it * 128 + 64 + sub * 4);
      float vf[8]; bf2f8(vb, vf);
      #pragma unroll
      for (int d = 0; d < 8; ++d) acc[d] += wt * vf[d];
    }

    #pragma unroll
    for (int off = 16; off <= 32; off <<= 1) {
      #pragma unroll
      for (int d = 0; d < 8; ++d) acc[d] += __shfl_xor(acc[d], off);
    }

    float ss = 0.f;
    #pragma unroll
    for (int d = 0; d < 8; ++d) ss += acc[d] * acc[d];
    ss += __shfl_xor(ss, 1); ss += __shfl_xor(ss, 2);
    ss += __shfl_xor(ss, 4); ss += __shfl_xor(ss, 8);
    float inv = 1.0f / fmaxf(sqrtf(ss), 1e-12f);
    #pragma unroll
    for (int d = 0; d < 8; ++d) acc[d] *= inv;

    if (slot == 0) {
      const float* bs = resUInit ? resUInit : resU;
      float4 b0 = ((const float4*)(bs + (size_t)u * DD))[sub * 2];
      float4 b1 = ((const float4*)(bs + (size_t)u * DD))[sub * 2 + 1];
      b0.x += acc[0]; b0.y += acc[1]; b0.z += acc[2]; b0.w += acc[3];
      b1.x += acc[4]; b1.y += acc[5]; b1.z += acc[6]; b1.w += acc[7];
      ((float4*)(resU + (size_t)u * DD))[sub * 2]     = b0;
      ((float4*)(resU + (size_t)u * DD))[sub * 2 + 1] = b1;
    }
  }
}

extern "C" void kernel_launch(void* const* d_in, const int* in_sizes, int n_in,
                              void* d_out, int out_size, void* d_ws, size_t ws_size,
                              hipStream_t stream) {
  const float* user_emb   = (const float*)d_in[0];
  const float* entity_emb = (const float*)d_in[1];
  const float* W_Q        = (const float*)d_in[2];
  const float* rel_emb    = (const float*)d_in[3];
  const int*   edge_index = (const int*)d_in[4];
  const int*   edge_type  = (const int*)d_in[5];
  const int*   inter_edge = (const int*)d_in[6];
  const float* inter_w    = (const float*)d_in[7];

  float* out_user = (float*)d_out;                       // N_USR*DD
  float* out_ent  = out_user + (size_t)N_USR * DD;       // N_ENT*DD

  char* p = (char*)d_ws;
  unsigned* IT1   = (unsigned*)p; p += (size_t)N_ENT * 128 * 4;  // hop1 interleaved T|ent
  unsigned* IT2   = (unsigned*)p; p += (size_t)N_ENT * 128 * 4;  // hop2 interleaved T|ent
  unsigned* relB  = (unsigned*)p; p += (size_t)9 * 64 * 4;
  uint4*    Wp    = (uint4*)p;    p += (size_t)2048 * 16;        // bf16 W fragments
  int* degE      = (int*)p;   p += (size_t)N_ENT * 4;            // degE+degU contiguous
  int* degU      = (int*)p;   p += (size_t)N_USR * 4;
  int* startsE   = (int*)p;   p += (size_t)(N_ENT + 1) * 4;
  int* startsU   = (int*)p;   p += (size_t)(N_USR + 1) * 4;
  int* cursorE   = (int*)p;   p += (size_t)N_ENT * 4;
  int* cursorU   = (int*)p;   p += (size_t)N_USR * 4;
  int* blkSum    = (int*)p;   p += (size_t)NBLK_SCAN * 4;
  int* blkOff    = (int*)p;   p += (size_t)NBLK_SCAN * 4;
  int* packE     = (int*)p;   p += (size_t)NE * 4;
  int* itemU     = (int*)p;   p += (size_t)NUI * 4;
  float* wUarr   = (float*)p; p += (size_t)NUI * 4;

  // ---- CSR build + bf16 conversions ----
  hipMemsetAsync(degE, 0, (size_t)(N_ENT + N_USR) * 4, stream);
  k_prep<<<(N_ENT * 16 + 255) / 256, 256, 0, stream>>>(edge_index, inter_edge, degE, degU,
                                                       entity_emb, IT1, rel_emb, relB, W_Q, Wp);
  k_scanA<<<NBLK_SCAN, 256, 0, stream>>>(degE, degU, startsE, startsU, blkSum);
  k_scanB<<<1, 256, 0, stream>>>(blkSum, blkOff, startsE, startsU);
  k_scanC<<<NBLK_SCAN, 256, 0, stream>>>(startsE, startsU, cursorE, cursorU, blkOff);
  k_scatter_all<<<(NE + NUI + 255) / 256, 256, 0, stream>>>(edge_index, edge_type, inter_edge, inter_w,
                                                            cursorE, cursorU, packE, itemU, wUarr);

  // ---- hop 1 ----
  k_gemm<<<(N_ENT + 63) / 64, 256, 0, stream>>>(IT1, Wp);
  k_node<<<NW / 4, 256, 0, stream>>>(IT1, relB, packE, startsE, itemU, wUarr, startsU,
                                     IT2, out_ent, entity_emb, out_user, user_emb);

  // ---- hop 2 ----
  k_gemm<<<(N_ENT + 63) / 64, 256, 0, stream>>>(IT2, Wp);
  k_node<<<NW / 4, 256, 0, stream>>>(IT2, relB, packE, startsE, itemU, wUarr, startsU,
                                     (unsigned*)nullptr, out_ent, (const float*)nullptr,
                                     out_user, (const float*)nullptr);
}